// Round 9
// baseline (183.204 us; speedup 1.0000x reference)
//
#include <hip/hip_runtime.h>
#include <math.h>

// Problem: X[16384,64] fp32, W[8192,64] fp32 -> argmin_c ||x-w_c||^2 (int32)
#define EMB     64
#define NTOK    8192
#define NQ      16384
#define TPB     256               // 4 waves: 2 q-halves x 2 c-halves
#define CSPLIT  8
#define CRANGE  (NTOK / CSPLIT)   // 1024 codewords per y-split
#define BQ      128               // query rows per block
#define TILE_C  64                // codewords per iteration
#define NT      (CRANGE / TILE_C) // 16 tiles
#define NXBLK   (NQ / BQ)         // 128
#define WCH     256               // chunks per wave-half-tile (4KB)

typedef _Float16 half8 __attribute__((ext_vector_type(8)));
typedef float    f32x4 __attribute__((ext_vector_type(4)));

// async global->LDS DMA, 16B per lane (dest = wave-uniform base + lane*16)
__device__ __forceinline__ void gl2lds16(const _Float16* g, _Float16* l) {
    __builtin_amdgcn_global_load_lds(
        (const __attribute__((address_space(1))) unsigned int*)g,
        (__attribute__((address_space(3))) unsigned int*)l, 16, 0, 0);
}

// monotone float->uint map: m(a) < m(b) iff a < b (no NaNs here)
__device__ __forceinline__ unsigned long long pack_di(float d, int idx) {
    unsigned int u = __float_as_uint(d);
    unsigned int m = (u & 0x80000000u) ? ~u : (u | 0x80000000u);
    return ((unsigned long long)m << 32) | (unsigned int)idx;
}

// ---------------------------------------------------------------------------
// Prep (chunk-parallel, verified r7/r8): split W into fp16 hi/lo in
// MFMA-FRAGMENT ORDER (thread per 16B chunk), ||w_c||^2 fp32 (thread per
// row), + init packed[]/cnt[]. Bit-identical Wh/Wl/ynorm vs r3-r8.
// Chunk u: u = g*128 + kb*64 + lq*16 + r, c = g*16+r, k0 = kb*32+lq*8.
// ---------------------------------------------------------------------------
__global__ void prep_kernel(const float* __restrict__ W,
                            _Float16* __restrict__ Wh, _Float16* __restrict__ Wl,
                            float* __restrict__ ynorm,
                            unsigned long long* __restrict__ packed,
                            int* __restrict__ cnt) {
    const int gtid = blockIdx.x * blockDim.x + threadIdx.x;   // 0..73727
    if (gtid < NQ)    packed[gtid] = ~0ull;
    if (gtid < NXBLK) cnt[gtid] = 0;
    if (gtid < NTOK * 8) {
        const int u  = gtid;
        const int g  = u >> 7, rem = u & 127;
        const int kb = rem >> 6, ln = rem & 63;
        const int r  = ln & 15, lq = ln >> 4;
        const int c  = g * 16 + r;
        const float* wp = W + (size_t)c * EMB + kb * 32 + lq * 8;
        float4 v0 = *(const float4*)wp;
        float4 v1 = *(const float4*)(wp + 4);
        float xv[8] = {v0.x, v0.y, v0.z, v0.w, v1.x, v1.y, v1.z, v1.w};
        half8 h, l;
#pragma unroll
        for (int j = 0; j < 8; ++j) {
            _Float16 hh = (_Float16)xv[j];
            h[j] = hh;
            l[j] = (_Float16)(xv[j] - (float)hh);
        }
        *(half8*)(Wh + (size_t)u * 8) = h;
        *(half8*)(Wl + (size_t)u * 8) = l;
    } else if (gtid < NTOK * 8 + NTOK) {
        const int c = gtid - NTOK * 8;
        const float4* w4 = (const float4*)(W + (size_t)c * EMB);
        float s = 0.f;
#pragma unroll
        for (int i = 0; i < EMB / 4; ++i) {
            float4 v = w4[i];
            s = fmaf(v.x, v.x, s); s = fmaf(v.y, v.y, s);
            s = fmaf(v.z, v.z, s); s = fmaf(v.w, v.w, s);
        }
        ynorm[c] = s;
    }
}

// ---------------------------------------------------------------------------
// Main: fp16 3-TERM split MFMA distance + argmin, BARRIER-FREE main loop
// (r8 structure, verified) at DOUBLE OCCUPANCY: TILE_C=64 / CSPLIT=8 shrink
// the block to ~38KB LDS -> 4 blocks/CU = 16 waves/CU = 4 waves/SIMD.
// Each wave owns a private 2-deep LDS buffer for its 32-col half-tile; per
// tile: [blr: 4 Wl reg loads][stage(t+1): 4 gl2lds16][s_waitcnt vmcnt(4)]
// [compute 2 ct x 4 mt x 6 MFMA + argmin epilogue]. No barrier in loop.
// Ends in the fence-free atomic combine (verified r6).
// Session notes (measured):
//  - __launch_bounds__ arg2 = min WORKGROUPS/CU (r2: cap 64 VGPR => spill)
//  - coop grid.sync 3x slower (r4); __threadfence finisher +34us (r5)
//  - sync-structure ablation r6/r7/r8: all ~66us -> sync not the bind;
//    ~35% both-pipes-idle at 2 waves/SIMD is the remaining target.
//  - 3-term split + atomic combine verified absmax=0 (r5-r8).
// ---------------------------------------------------------------------------
__global__ __launch_bounds__(TPB, 4) void vq_mfma_kernel(
    const float* __restrict__ X,
    const _Float16* __restrict__ Wh, const _Float16* __restrict__ Wl,
    const float* __restrict__ ynorm,
    unsigned long long* __restrict__ packed,
    int* __restrict__ cnt, int* __restrict__ out)
{
    __shared__ __align__(16) _Float16 LdsP[4][2][WCH * 8];  // 32KB: per-wave 2-deep
    __shared__ __align__(16) float    Lyn[CRANGE];          // 4KB
    __shared__ float RedV[2][BQ];
    __shared__ int   RedI[2][BQ];
    __shared__ int   fin;

    const int t    = threadIdx.x;
    const int lane = t & 63;
    const int wid  = t >> 6;       // 0..3
    const int wq   = wid & 1;      // q half (0/1)
    const int wy   = wid >> 1;     // c half (0/1)
    const int l15  = lane & 15;
    const int lq   = lane >> 4;    // 0..3

    const int bx     = blockIdx.x;
    const int qblk   = bx * BQ;
    const int qbase  = qblk + wq * 64;
    const int cbase0 = blockIdx.y * CRANGE;

    _Float16* const myP0 = &LdsP[wid][0][0];
    _Float16* const myP1 = &LdsP[wid][1][0];

    // --- prologue: stage tile 0's half into private buf0 (issued first) ---
    {
        const size_t gch = (size_t)cbase0 * 8 + wy * WCH;   // chunk id base
#pragma unroll
        for (int i = 0; i < 4; ++i)
            gl2lds16(Wh + (gch + i * 64 + lane) * 8, myP0 + (size_t)i * 64 * 8);
    }

    // --- stage the block's full ynorm range once ---
    for (int u = t; u < CRANGE / 4; u += TPB)
        ((float4*)Lyn)[u] = ((const float4*)(ynorm + cbase0))[u];

    // --- A fragments: X rows (qbase + mt*16 + l15), k = kb*32 + lq*8 + j ---
    half8 ah[4][2], al[4][2];
#pragma unroll
    for (int mt = 0; mt < 4; ++mt) {
#pragma unroll
        for (int kb = 0; kb < 2; ++kb) {
            const float* xp = X + (size_t)(qbase + mt * 16 + l15) * EMB + kb * 32 + lq * 8;
            float4 v0 = *(const float4*)xp;
            float4 v1 = *(const float4*)(xp + 4);
            float xv[8] = {v0.x, v0.y, v0.z, v0.w, v1.x, v1.y, v1.z, v1.w};
            half8 h, l;
#pragma unroll
            for (int j = 0; j < 8; ++j) {
                _Float16 hh = (_Float16)xv[j];
                h[j] = hh;
                l[j] = (_Float16)(xv[j] - (float)hh);
            }
            ah[mt][kb] = h;
            al[mt][kb] = l;
        }
    }

    float minv[4][4];
    int   mini[4][4];
#pragma unroll
    for (int mt = 0; mt < 4; ++mt)
#pragma unroll
        for (int r = 0; r < 4; ++r) { minv[mt][r] = INFINITY; mini[mt][r] = 0; }

    const f32x4 zero4 = {0.f, 0.f, 0.f, 0.f};

    __syncthreads();   // one-time: Lyn visible; drains tile-0 DMA too

#pragma unroll 1
    for (int tt = 0; tt < NT; ++tt) {
        const int    cb  = cbase0 + tt * TILE_C;
        const size_t gch = (size_t)cb * 8 + wy * WCH;   // this wave's half-tile chunks

        // --- (1) Wl lo-fragments for THIS tile -> regs (4 vmem) ---
        half8 blr[2][2];
#pragma unroll
        for (int ct = 0; ct < 2; ++ct) {
            blr[ct][0] = *(const half8*)(Wl + (gch + ct * 128 + lane) * 8);
            blr[ct][1] = *(const half8*)(Wl + (gch + ct * 128 + 64 + lane) * 8);
        }

        // --- (2) stage tile tt+1's half into the other private buf (4 vmem) ---
        if (tt + 1 < NT) {
            const size_t gnx = gch + TILE_C * 8;
            _Float16* dst = (tt & 1) ? myP0 : myP1;     // buf (tt+1)&1
#pragma unroll
            for (int i = 0; i < 4; ++i)
                gl2lds16(Wh + (gnx + i * 64 + lane) * 8, dst + (size_t)i * 64 * 8);
        }

        // --- (3) counted wait: stage(tt)+blr retired; stage(tt+1) stays in
        // flight. Per-wave vmcnt -> no cross-wave coupling, no barrier. ---
        asm volatile("s_waitcnt vmcnt(4)" ::: "memory");
        __builtin_amdgcn_sched_barrier(0);

        // --- (4) compute tile tt from private buf (tt&1) + blr ---
        const _Float16* LB = (tt & 1) ? myP1 : myP0;
        const int c0 = tt * TILE_C;
#pragma unroll
        for (int ct = 0; ct < 2; ++ct) {
            half8 bh0 = *(const half8*)(LB + (size_t)(ct * 128 + lane) * 8);
            half8 bh1 = *(const half8*)(LB + (size_t)(ct * 128 + 64 + lane) * 8);
            f32x4 acc[4];
#pragma unroll
            for (int mt = 0; mt < 4; ++mt) {
                // 3-term: al*bh + ah*bl + ah*bh per kb (verified r5-r8, absmax=0)
                f32x4 a = __builtin_amdgcn_mfma_f32_16x16x32_f16(al[mt][0], bh0, zero4, 0, 0, 0);
                a = __builtin_amdgcn_mfma_f32_16x16x32_f16(ah[mt][0], blr[ct][0], a, 0, 0, 0);
                a = __builtin_amdgcn_mfma_f32_16x16x32_f16(ah[mt][0], bh0, a, 0, 0, 0);
                a = __builtin_amdgcn_mfma_f32_16x16x32_f16(al[mt][1], bh1, a, 0, 0, 0);
                a = __builtin_amdgcn_mfma_f32_16x16x32_f16(ah[mt][1], blr[ct][1], a, 0, 0, 0);
                a = __builtin_amdgcn_mfma_f32_16x16x32_f16(ah[mt][1], bh1, a, 0, 0, 0);
                acc[mt] = a;
            }
            // --- epilogue: dist = ynorm - 2*dot; running argmin (c asc, strict <) ---
            const int   ccol = wy * 32 + ct * 16;
            const float yn   = Lyn[c0 + ccol + l15];
            const int   cidx = cb + ccol + l15;
#pragma unroll
            for (int mt = 0; mt < 4; ++mt) {
#pragma unroll
                for (int r = 0; r < 4; ++r) {
                    float s = fmaf(-2.f, acc[mt][r], yn);
                    if (s < minv[mt][r]) { minv[mt][r] = s; mini[mt][r] = cidx; }
                }
            }
        }
        // no barrier: waves free-run on private buffers
    }

    // --- cross-lane: reduce over the 16 col-lanes (xor on low 4 lane bits) ---
#pragma unroll
    for (int mt = 0; mt < 4; ++mt) {
#pragma unroll
        for (int r = 0; r < 4; ++r) {
            float v = minv[mt][r];
            int   i = mini[mt][r];
#pragma unroll
            for (int m = 1; m <= 8; m <<= 1) {
                float ov = __shfl_xor(v, m, 64);
                int   oi = __shfl_xor(i, m, 64);
                if (ov < v || (ov == v && oi < i)) { v = ov; i = oi; }
            }
            if (l15 == 0) {
                int qoff = wq * 64 + mt * 16 + lq * 4 + r;   // row within block
                RedV[wy][qoff] = v;
                RedI[wy][qoff] = i;
            }
        }
    }
    __syncthreads();

    // --- combine c-halves, then FENCE-FREE cross-split combine via atomics ---
    if (t < BQ) {
        float v0 = RedV[0][t]; int i0 = RedI[0][t];
        float v1 = RedV[1][t]; int i1 = RedI[1][t];
        if (v1 < v0 || (v1 == v0 && i1 < i0)) { v0 = v1; i0 = i1; }
        atomicMin(&packed[qblk + t], pack_di(v0, i0));   // device-scope, coherent
    }
    // ensure this block's atomicMins are globally performed before the ticket
    asm volatile("s_waitcnt vmcnt(0)" ::: "memory");
    __syncthreads();
    if (t == 0) fin = (atomicAdd(&cnt[bx], 1) == CSPLIT - 1);
    __syncthreads();
    if (fin && t < BQ) {
        // atomic read-back (atomicMin with identity) -> final packed value
        unsigned long long v = atomicMin(&packed[qblk + t], ~0ull);
        out[qblk + t] = (int)(unsigned int)(v & 0xFFFFFFFFu);
    }
}

// ---------------------------------------------------------------------------
extern "C" void kernel_launch(void* const* d_in, const int* in_sizes, int n_in,
                              void* d_out, int out_size, void* d_ws, size_t ws_size,
                              hipStream_t stream) {
    const float* X = (const float*)d_in[0];   // [16384, 64]
    const float* W = (const float*)d_in[1];   // [8192, 64]

    // ws layout: Wh(1MB) | Wl(1MB) | ynorm(32KB) | packed(128KB) | cnt(512B)
    _Float16* Wh    = (_Float16*)d_ws;
    _Float16* Wl    = Wh + (size_t)NTOK * EMB;
    float*    ynorm = (float*)(Wl + (size_t)NTOK * EMB);
    unsigned long long* packed = (unsigned long long*)(ynorm + NTOK);
    int*      cnt   = (int*)(packed + NQ);
    int*      out   = (int*)d_out;

    prep_kernel<<<(NTOK * 8 + NTOK) / TPB, TPB, 0, stream>>>(W, Wh, Wl, ynorm, packed, cnt);
    dim3 grid(NXBLK, CSPLIT);
    vq_mfma_kernel<<<grid, TPB, 0, stream>>>(X, Wh, Wl, ynorm, packed, cnt, out);
}

// Round 10
// 124.356 us; speedup vs baseline: 1.4732x; 1.4732x over previous
//
#include <hip/hip_runtime.h>
#include <math.h>

// Problem: X[16384,64] fp32, W[8192,64] fp32 -> argmin_c ||x-w_c||^2 (int32)
#define EMB     64
#define NTOK    8192
#define NQ      16384
#define TPB     256               // 4 waves: 2 q-halves x 2 c-halves
#define CSPLIT  8
#define CRANGE  (NTOK / CSPLIT)   // 1024 codewords per y-split
#define BQ      128               // query rows per block
#define TILE_C  64                // codewords per iteration
#define NT      (CRANGE / TILE_C) // 16 tiles
#define NXBLK   (NQ / BQ)         // 128
#define WCH     256               // chunks per wave-half-tile (4KB)

typedef _Float16 half8 __attribute__((ext_vector_type(8)));
typedef float    f32x4 __attribute__((ext_vector_type(4)));

// async global->LDS DMA, 16B per lane (dest = wave-uniform base + lane*16)
__device__ __forceinline__ void gl2lds16(const _Float16* g, _Float16* l) {
    __builtin_amdgcn_global_load_lds(
        (const __attribute__((address_space(1))) unsigned int*)g,
        (__attribute__((address_space(3))) unsigned int*)l, 16, 0, 0);
}

// monotone float->uint map: m(a) < m(b) iff a < b (no NaNs here)
__device__ __forceinline__ unsigned long long pack_di(float d, int idx) {
    unsigned int u = __float_as_uint(d);
    unsigned int m = (u & 0x80000000u) ? ~u : (u | 0x80000000u);
    return ((unsigned long long)m << 32) | (unsigned int)idx;
}

// ---------------------------------------------------------------------------
// Prep (chunk-parallel, verified r7/r8): split W into fp16 hi/lo in
// MFMA-FRAGMENT ORDER (thread per 16B chunk), ||w_c||^2 fp32 (thread per
// row), + init packed[]/cnt[]. Bit-identical Wh/Wl/ynorm vs r3-r9.
// Chunk u: u = g*128 + kb*64 + lq*16 + r, c = g*16+r, k0 = kb*32+lq*8.
// ---------------------------------------------------------------------------
__global__ void prep_kernel(const float* __restrict__ W,
                            _Float16* __restrict__ Wh, _Float16* __restrict__ Wl,
                            float* __restrict__ ynorm,
                            unsigned long long* __restrict__ packed,
                            int* __restrict__ cnt) {
    const int gtid = blockIdx.x * blockDim.x + threadIdx.x;   // 0..73727
    if (gtid < NQ)    packed[gtid] = ~0ull;
    if (gtid < NXBLK) cnt[gtid] = 0;
    if (gtid < NTOK * 8) {
        const int u  = gtid;
        const int g  = u >> 7, rem = u & 127;
        const int kb = rem >> 6, ln = rem & 63;
        const int r  = ln & 15, lq = ln >> 4;
        const int c  = g * 16 + r;
        const float* wp = W + (size_t)c * EMB + kb * 32 + lq * 8;
        float4 v0 = *(const float4*)wp;
        float4 v1 = *(const float4*)(wp + 4);
        float xv[8] = {v0.x, v0.y, v0.z, v0.w, v1.x, v1.y, v1.z, v1.w};
        half8 h, l;
#pragma unroll
        for (int j = 0; j < 8; ++j) {
            _Float16 hh = (_Float16)xv[j];
            h[j] = hh;
            l[j] = (_Float16)(xv[j] - (float)hh);
        }
        *(half8*)(Wh + (size_t)u * 8) = h;
        *(half8*)(Wl + (size_t)u * 8) = l;
    } else if (gtid < NTOK * 8 + NTOK) {
        const int c = gtid - NTOK * 8;
        const float4* w4 = (const float4*)(W + (size_t)c * EMB);
        float s = 0.f;
#pragma unroll
        for (int i = 0; i < EMB / 4; ++i) {
            float4 v = w4[i];
            s = fmaf(v.x, v.x, s); s = fmaf(v.y, v.y, s);
            s = fmaf(v.z, v.z, s); s = fmaf(v.w, v.w, s);
        }
        ynorm[c] = s;
    }
}

// ---------------------------------------------------------------------------
// Main: fp16 3-TERM split MFMA distance + argmin, BARRIER-FREE main loop
// (r8 structure, verified) at 4-blocks/CU geometry: TILE_C=64 / CSPLIT=8,
// ~38.5KB LDS. Occupancy comes from ACTUAL register usage (~90-105 VGPR
// <= 128 -> 4 waves/SIMD; LDS -> 4 blocks/CU; grid 1024 = 4/CU x 256 CU).
// Each wave owns a private 2-deep LDS buffer for its 32-col half-tile; per
// tile: [blr: 4 Wl reg loads][stage(t+1): 4 gl2lds16][s_waitcnt vmcnt(4)]
// [compute 2 ct x 4 mt x 6 MFMA + argmin epilogue]. No barrier in loop.
// Ends in the fence-free atomic combine (verified r6).
// Session notes (measured -- DO NOT regress):
//  - __launch_bounds__ arg2: 3 -> cap ~170 (ok); 2 -> cap ~128 (ok);
//    >=4 -> cap 64 VGPR = total spill (r2 AND r9, both block sizes).
//    NEVER use arg2 >= 4 with this kernel's ~100-reg state.
//  - coop grid.sync 3x slower (r4); __threadfence finisher +34us (r5)
//  - sync-structure ablation r6/r7/r8: all ~66us -> sync not the bind;
//    ~35% both-pipes-idle at 2 waves/SIMD is the target of this round.
//  - 3-term split + atomic combine verified absmax=0 (r5-r8).
// ---------------------------------------------------------------------------
__global__ __launch_bounds__(TPB, 2) void vq_mfma_kernel(
    const float* __restrict__ X,
    const _Float16* __restrict__ Wh, const _Float16* __restrict__ Wl,
    const float* __restrict__ ynorm,
    unsigned long long* __restrict__ packed,
    int* __restrict__ cnt, int* __restrict__ out)
{
    __shared__ __align__(16) _Float16 LdsP[4][2][WCH * 8];  // 32KB: per-wave 2-deep
    __shared__ __align__(16) float    Lyn[CRANGE];          // 4KB
    __shared__ float RedV[2][BQ];
    __shared__ int   RedI[2][BQ];
    __shared__ int   fin;

    const int t    = threadIdx.x;
    const int lane = t & 63;
    const int wid  = t >> 6;       // 0..3
    const int wq   = wid & 1;      // q half (0/1)
    const int wy   = wid >> 1;     // c half (0/1)
    const int l15  = lane & 15;
    const int lq   = lane >> 4;    // 0..3

    const int bx     = blockIdx.x;
    const int qblk   = bx * BQ;
    const int qbase  = qblk + wq * 64;
    const int cbase0 = blockIdx.y * CRANGE;

    _Float16* const myP0 = &LdsP[wid][0][0];
    _Float16* const myP1 = &LdsP[wid][1][0];

    // --- prologue: stage tile 0's half into private buf0 (issued first) ---
    {
        const size_t gch = (size_t)cbase0 * 8 + wy * WCH;   // chunk id base
#pragma unroll
        for (int i = 0; i < 4; ++i)
            gl2lds16(Wh + (gch + i * 64 + lane) * 8, myP0 + (size_t)i * 64 * 8);
    }

    // --- stage the block's full ynorm range once ---
    for (int u = t; u < CRANGE / 4; u += TPB)
        ((float4*)Lyn)[u] = ((const float4*)(ynorm + cbase0))[u];

    // --- A fragments: X rows (qbase + mt*16 + l15), k = kb*32 + lq*8 + j ---
    half8 ah[4][2], al[4][2];
#pragma unroll
    for (int mt = 0; mt < 4; ++mt) {
#pragma unroll
        for (int kb = 0; kb < 2; ++kb) {
            const float* xp = X + (size_t)(qbase + mt * 16 + l15) * EMB + kb * 32 + lq * 8;
            float4 v0 = *(const float4*)xp;
            float4 v1 = *(const float4*)(xp + 4);
            float xv[8] = {v0.x, v0.y, v0.z, v0.w, v1.x, v1.y, v1.z, v1.w};
            half8 h, l;
#pragma unroll
            for (int j = 0; j < 8; ++j) {
                _Float16 hh = (_Float16)xv[j];
                h[j] = hh;
                l[j] = (_Float16)(xv[j] - (float)hh);
            }
            ah[mt][kb] = h;
            al[mt][kb] = l;
        }
    }

    float minv[4][4];
    int   mini[4][4];
#pragma unroll
    for (int mt = 0; mt < 4; ++mt)
#pragma unroll
        for (int r = 0; r < 4; ++r) { minv[mt][r] = INFINITY; mini[mt][r] = 0; }

    const f32x4 zero4 = {0.f, 0.f, 0.f, 0.f};

    __syncthreads();   // one-time: Lyn visible; drains tile-0 DMA too

#pragma unroll 1
    for (int tt = 0; tt < NT; ++tt) {
        const int    cb  = cbase0 + tt * TILE_C;
        const size_t gch = (size_t)cb * 8 + wy * WCH;   // this wave's half-tile chunks

        // --- (1) Wl lo-fragments for THIS tile -> regs (4 vmem) ---
        half8 blr[2][2];
#pragma unroll
        for (int ct = 0; ct < 2; ++ct) {
            blr[ct][0] = *(const half8*)(Wl + (gch + ct * 128 + lane) * 8);
            blr[ct][1] = *(const half8*)(Wl + (gch + ct * 128 + 64 + lane) * 8);
        }

        // --- (2) stage tile tt+1's half into the other private buf (4 vmem) ---
        if (tt + 1 < NT) {
            const size_t gnx = gch + TILE_C * 8;
            _Float16* dst = (tt & 1) ? myP0 : myP1;     // buf (tt+1)&1
#pragma unroll
            for (int i = 0; i < 4; ++i)
                gl2lds16(Wh + (gnx + i * 64 + lane) * 8, dst + (size_t)i * 64 * 8);
        }

        // --- (3) counted wait: stage(tt)+blr retired; stage(tt+1) stays in
        // flight. Per-wave vmcnt -> no cross-wave coupling, no barrier. ---
        asm volatile("s_waitcnt vmcnt(4)" ::: "memory");
        __builtin_amdgcn_sched_barrier(0);

        // --- (4) compute tile tt from private buf (tt&1) + blr ---
        const _Float16* LB = (tt & 1) ? myP1 : myP0;
        const int c0 = tt * TILE_C;
#pragma unroll
        for (int ct = 0; ct < 2; ++ct) {
            half8 bh0 = *(const half8*)(LB + (size_t)(ct * 128 + lane) * 8);
            half8 bh1 = *(const half8*)(LB + (size_t)(ct * 128 + 64 + lane) * 8);
            f32x4 acc[4];
#pragma unroll
            for (int mt = 0; mt < 4; ++mt) {
                // 3-term: al*bh + ah*bl + ah*bh per kb (verified r5-r8, absmax=0)
                f32x4 a = __builtin_amdgcn_mfma_f32_16x16x32_f16(al[mt][0], bh0, zero4, 0, 0, 0);
                a = __builtin_amdgcn_mfma_f32_16x16x32_f16(ah[mt][0], blr[ct][0], a, 0, 0, 0);
                a = __builtin_amdgcn_mfma_f32_16x16x32_f16(ah[mt][0], bh0, a, 0, 0, 0);
                a = __builtin_amdgcn_mfma_f32_16x16x32_f16(al[mt][1], bh1, a, 0, 0, 0);
                a = __builtin_amdgcn_mfma_f32_16x16x32_f16(ah[mt][1], blr[ct][1], a, 0, 0, 0);
                a = __builtin_amdgcn_mfma_f32_16x16x32_f16(ah[mt][1], bh1, a, 0, 0, 0);
                acc[mt] = a;
            }
            // --- epilogue: dist = ynorm - 2*dot; running argmin (c asc, strict <) ---
            const int   ccol = wy * 32 + ct * 16;
            const float yn   = Lyn[c0 + ccol + l15];
            const int   cidx = cb + ccol + l15;
#pragma unroll
            for (int mt = 0; mt < 4; ++mt) {
#pragma unroll
                for (int r = 0; r < 4; ++r) {
                    float s = fmaf(-2.f, acc[mt][r], yn);
                    if (s < minv[mt][r]) { minv[mt][r] = s; mini[mt][r] = cidx; }
                }
            }
        }
        // no barrier: waves free-run on private buffers
    }

    // --- cross-lane: reduce over the 16 col-lanes (xor on low 4 lane bits) ---
#pragma unroll
    for (int mt = 0; mt < 4; ++mt) {
#pragma unroll
        for (int r = 0; r < 4; ++r) {
            float v = minv[mt][r];
            int   i = mini[mt][r];
#pragma unroll
            for (int m = 1; m <= 8; m <<= 1) {
                float ov = __shfl_xor(v, m, 64);
                int   oi = __shfl_xor(i, m, 64);
                if (ov < v || (ov == v && oi < i)) { v = ov; i = oi; }
            }
            if (l15 == 0) {
                int qoff = wq * 64 + mt * 16 + lq * 4 + r;   // row within block
                RedV[wy][qoff] = v;
                RedI[wy][qoff] = i;
            }
        }
    }
    __syncthreads();

    // --- combine c-halves, then FENCE-FREE cross-split combine via atomics ---
    if (t < BQ) {
        float v0 = RedV[0][t]; int i0 = RedI[0][t];
        float v1 = RedV[1][t]; int i1 = RedI[1][t];
        if (v1 < v0 || (v1 == v0 && i1 < i0)) { v0 = v1; i0 = i1; }
        atomicMin(&packed[qblk + t], pack_di(v0, i0));   // device-scope, coherent
    }
    // ensure this block's atomicMins are globally performed before the ticket
    asm volatile("s_waitcnt vmcnt(0)" ::: "memory");
    __syncthreads();
    if (t == 0) fin = (atomicAdd(&cnt[bx], 1) == CSPLIT - 1);
    __syncthreads();
    if (fin && t < BQ) {
        // atomic read-back (atomicMin with identity) -> final packed value
        unsigned long long v = atomicMin(&packed[qblk + t], ~0ull);
        out[qblk + t] = (int)(unsigned int)(v & 0xFFFFFFFFu);
    }
}

// ---------------------------------------------------------------------------
extern "C" void kernel_launch(void* const* d_in, const int* in_sizes, int n_in,
                              void* d_out, int out_size, void* d_ws, size_t ws_size,
                              hipStream_t stream) {
    const float* X = (const float*)d_in[0];   // [16384, 64]
    const float* W = (const float*)d_in[1];   // [8192, 64]

    // ws layout: Wh(1MB) | Wl(1MB) | ynorm(32KB) | packed(128KB) | cnt(512B)
    _Float16* Wh    = (_Float16*)d_ws;
    _Float16* Wl    = Wh + (size_t)NTOK * EMB;
    float*    ynorm = (float*)(Wl + (size_t)NTOK * EMB);
    unsigned long long* packed = (unsigned long long*)(ynorm + NTOK);
    int*      cnt   = (int*)(packed + NQ);
    int*      out   = (int*)d_out;

    prep_kernel<<<(NTOK * 8 + NTOK) / TPB, TPB, 0, stream>>>(W, Wh, Wl, ynorm, packed, cnt);
    dim3 grid(NXBLK, CSPLIT);
    vq_mfma_kernel<<<grid, TPB, 0, stream>>>(X, Wh, Wl, ynorm, packed, cnt, out);
}

// Round 11
// 113.303 us; speedup vs baseline: 1.6169x; 1.0976x over previous
//
#include <hip/hip_runtime.h>
#include <math.h>

// Problem: X[16384,64] fp32, W[8192,64] fp32 -> argmin_c ||x-w_c||^2 (int32)
#define EMB     64
#define NTOK    8192
#define NQ      16384
#define TPB     256               // 4 waves: 2 q-halves x 2 c-halves
#define CSPLIT  4
#define CRANGE  (NTOK / CSPLIT)   // 2048 codewords per y-split
#define BQ      128               // query rows per block
#define TILE_C  128               // codewords staged in LDS per iteration
#define NT      (CRANGE / TILE_C) // 16 tiles
#define TCH     (TILE_C * EMB)    // halves per tile buffer (8192 = 16KB)
#define NXBLK   (NQ / BQ)         // 128

typedef _Float16 half8 __attribute__((ext_vector_type(8)));
typedef float    f32x4 __attribute__((ext_vector_type(4)));

// async global->LDS DMA, 16B per lane (dest = wave-uniform base + lane*16)
__device__ __forceinline__ void gl2lds16(const _Float16* g, _Float16* l) {
    __builtin_amdgcn_global_load_lds(
        (const __attribute__((address_space(1))) unsigned int*)g,
        (__attribute__((address_space(3))) unsigned int*)l, 16, 0, 0);
}

// monotone float->uint map: m(a) < m(b) iff a < b (no NaNs here)
__device__ __forceinline__ unsigned long long pack_di(float d, int idx) {
    unsigned int u = __float_as_uint(d);
    unsigned int m = (u & 0x80000000u) ? ~u : (u | 0x80000000u);
    return ((unsigned long long)m << 32) | (unsigned int)idx;
}

// ---------------------------------------------------------------------------
// Prep v3 -- COALESCED. One thread per input 8-float segment (65536 threads,
// 256 blocks): thread v reads row c = v>>3, seg = v&7 (wave reads contiguous
// 2KB -- the r6 row-based prep ran 64 blocks total; the r7 chunk-parallel
// prep gathered 64 cache lines per wave-load at 256B stride; both ~dozens of
// us of the ~50us total-vs-main gap). Writes Wh/Wl in MFMA-FRAGMENT ORDER
// (bit-identical bytes to the r5-r10-verified layout):
//   chunk u = g*128 + kb*64 + lq*16 + r holds W[g*16+r][kb*32+lq*8..+7],
//   here g=c>>4, r=c&15, kb=seg>>2, lq=seg&3.
// ynorm from the already-loaded xv via 3-step shfl_xor tree over the 8
// same-row lanes (lanes 8-aligned within the wave) -- kills the strided
// ynorm read pass. Tree-vs-sequential rounding ~1e-6 abs; argmin margins
// O(0.1..1) -- same tolerance class proven absmax=0 since r5.
// Also inits packed[]/cnt[] (gtid < NQ / NXBLK).
// ---------------------------------------------------------------------------
__global__ void prep_kernel(const float* __restrict__ W,
                            _Float16* __restrict__ Wh, _Float16* __restrict__ Wl,
                            float* __restrict__ ynorm,
                            unsigned long long* __restrict__ packed,
                            int* __restrict__ cnt) {
    const int gtid = blockIdx.x * blockDim.x + threadIdx.x;   // 0..65535
    if (gtid < NQ)    packed[gtid] = ~0ull;
    if (gtid < NXBLK) cnt[gtid] = 0;

    const int c   = gtid >> 3;          // input row (0..8191)
    const int seg = gtid & 7;           // 8-float segment within row
    const float* wp = W + (size_t)c * EMB + seg * 8;
    float4 v0 = *(const float4*)wp;     // coalesced: wave covers 2KB contiguous
    float4 v1 = *(const float4*)(wp + 4);
    float xv[8] = {v0.x, v0.y, v0.z, v0.w, v1.x, v1.y, v1.z, v1.w};
    half8 h, l;
    float s8 = 0.f;
#pragma unroll
    for (int j = 0; j < 8; ++j) {
        _Float16 hh = (_Float16)xv[j];
        h[j] = hh;
        l[j] = (_Float16)(xv[j] - (float)hh);
        s8 = fmaf(xv[j], xv[j], s8);
    }
    const int g = c >> 4, r = c & 15, kb = seg >> 2, lq = seg & 3;
    const size_t u = (size_t)g * 128 + kb * 64 + lq * 16 + r;
    *(half8*)(Wh + u * 8) = h;
    *(half8*)(Wl + u * 8) = l;

    // ynorm: tree-sum the 8 segment partials of row c (lanes gtid&~7 .. +7)
    s8 += __shfl_xor(s8, 1, 64);
    s8 += __shfl_xor(s8, 2, 64);
    s8 += __shfl_xor(s8, 4, 64);
    if (seg == 0) ynorm[c] = s8;
}

// ---------------------------------------------------------------------------
// Main: r6 VERBATIM -- best measured (65.2us). fp16 3-TERM split MFMA
// distance + argmin, 2-phase async-DMA pipeline (stage t+1 under compute t,
// vmcnt(0)+lgkmcnt(0)+s_barrier per tile), fence-free atomic combine.
// Session ledger (measured -- do not regress):
//  - __launch_bounds__ arg2: 3 -> cap ~170 ok; 2 -> ~128 ok; >=4 -> 64 VGPR
//    = total spill (r2, r9).
//  - coop grid.sync fusion 3x slower (r4); __threadfence finisher +34us (r5).
//  - sync ablation r6/r7/r8 all ~66us -> sync structure not the bind.
//  - occupancy: 4 waves/SIMD slower in BOTH regimes (r3 lockstep, r10
//    free-run 77us) -> 2 blocks/CU x 4 waves is the sweet spot.
//  - 3-term split + atomic combine verified absmax=0 (r5-r10).
// ---------------------------------------------------------------------------
__global__ __launch_bounds__(TPB, 3) void vq_mfma_kernel(
    const float* __restrict__ X,
    const _Float16* __restrict__ Wh, const _Float16* __restrict__ Wl,
    const float* __restrict__ ynorm,
    unsigned long long* __restrict__ packed,
    int* __restrict__ cnt, int* __restrict__ out)
{
    __shared__ __align__(16) _Float16 LdsH0[TCH];
    __shared__ __align__(16) _Float16 LdsH1[TCH];
    __shared__ __align__(16) _Float16 LdsL0[TCH];
    __shared__ __align__(16) _Float16 LdsL1[TCH];
    __shared__ __align__(16) float    Lyn[CRANGE];
    __shared__ float RedV[2][BQ];
    __shared__ int   RedI[2][BQ];
    __shared__ int   fin;

    const int t    = threadIdx.x;
    const int lane = t & 63;
    const int wid  = t >> 6;       // 0..3
    const int wq   = wid & 1;      // q half (0/1)
    const int wy   = wid >> 1;     // c half (0/1)
    const int l15  = lane & 15;
    const int lq   = lane >> 4;    // 0..3

    const int bx     = blockIdx.x;
    const int qblk   = bx * BQ;
    const int qbase  = qblk + wq * 64;
    const int cbase0 = blockIdx.y * CRANGE;

    // --- issue tile-0 DMA first so it overlaps prologue work ---
    {
        const size_t gsbase = (size_t)(cbase0 >> 4) * 1024;   // halves
#pragma unroll
        for (int i = 0; i < 4; ++i) {
            const int jw = i * 256 + wid * 64;                // wave-uniform chunk base
            gl2lds16(Wh + gsbase + (size_t)(jw + lane) * 8, LdsH0 + (size_t)jw * 8);
            gl2lds16(Wl + gsbase + (size_t)(jw + lane) * 8, LdsL0 + (size_t)jw * 8);
        }
    }

    // --- stage the block's full ynorm range once ---
    for (int u = t; u < CRANGE / 4; u += TPB)
        ((float4*)Lyn)[u] = ((const float4*)(ynorm + cbase0))[u];

    // --- A fragments: X rows (qbase + mt*16 + l15), k = kb*32 + lq*8 + j ---
    half8 ah[4][2], al[4][2];
#pragma unroll
    for (int mt = 0; mt < 4; ++mt) {
#pragma unroll
        for (int kb = 0; kb < 2; ++kb) {
            const float* xp = X + (size_t)(qbase + mt * 16 + l15) * EMB + kb * 32 + lq * 8;
            float4 v0 = *(const float4*)xp;
            float4 v1 = *(const float4*)(xp + 4);
            float xv[8] = {v0.x, v0.y, v0.z, v0.w, v1.x, v1.y, v1.z, v1.w};
            half8 h, l;
#pragma unroll
            for (int j = 0; j < 8; ++j) {
                _Float16 hh = (_Float16)xv[j];
                h[j] = hh;
                l[j] = (_Float16)(xv[j] - (float)hh);
            }
            ah[mt][kb] = h;
            al[mt][kb] = l;
        }
    }

    float minv[4][4];
    int   mini[4][4];
#pragma unroll
    for (int mt = 0; mt < 4; ++mt)
#pragma unroll
        for (int r = 0; r < 4; ++r) { minv[mt][r] = INFINITY; mini[mt][r] = 0; }

    const f32x4 zero4 = {0.f, 0.f, 0.f, 0.f};

    __syncthreads();   // tile0 DMA + Lyn writes visible

    int cur = 0;
    for (int tt = 0; tt < NT; ++tt) {
        // --- STAGE tile tt+1 into the other buffer (async DMA, in flight under MFMAs) ---
        if (tt + 1 < NT) {
            const size_t gsbase = (size_t)((cbase0 + (tt + 1) * TILE_C) >> 4) * 1024;
            _Float16* dH = (cur ^ 1) ? LdsH1 : LdsH0;
            _Float16* dL = (cur ^ 1) ? LdsL1 : LdsL0;
#pragma unroll
            for (int i = 0; i < 4; ++i) {
                const int jw = i * 256 + wid * 64;
                gl2lds16(Wh + gsbase + (size_t)(jw + lane) * 8, dH + (size_t)jw * 8);
                gl2lds16(Wl + gsbase + (size_t)(jw + lane) * 8, dL + (size_t)jw * 8);
            }
        }

        // --- COMPUTE tile tt from buf cur ---
        const _Float16* LH = cur ? LdsH1 : LdsH0;
        const _Float16* LL = cur ? LdsL1 : LdsL0;
        const int c0 = tt * TILE_C;
#pragma unroll
        for (int ct = 0; ct < 4; ++ct) {
            const int chunk0 = (wy * 4 + ct) * 128 + lane;   // 64 consecutive chunks/wave
            half8 bh0 = *(const half8*)(LH + (size_t)chunk0 * 8);
            half8 bl0 = *(const half8*)(LL + (size_t)chunk0 * 8);
            half8 bh1 = *(const half8*)(LH + (size_t)(chunk0 + 64) * 8);
            half8 bl1 = *(const half8*)(LL + (size_t)(chunk0 + 64) * 8);
            f32x4 acc[4];
#pragma unroll
            for (int mt = 0; mt < 4; ++mt) {
                // 3-term: al*bh + ah*bl + ah*bh per kb (verified r5-r10, absmax=0)
                f32x4 a = __builtin_amdgcn_mfma_f32_16x16x32_f16(al[mt][0], bh0, zero4, 0, 0, 0);
                a = __builtin_amdgcn_mfma_f32_16x16x32_f16(ah[mt][0], bl0, a, 0, 0, 0);
                a = __builtin_amdgcn_mfma_f32_16x16x32_f16(ah[mt][0], bh0, a, 0, 0, 0);
                a = __builtin_amdgcn_mfma_f32_16x16x32_f16(al[mt][1], bh1, a, 0, 0, 0);
                a = __builtin_amdgcn_mfma_f32_16x16x32_f16(ah[mt][1], bl1, a, 0, 0, 0);
                a = __builtin_amdgcn_mfma_f32_16x16x32_f16(ah[mt][1], bh1, a, 0, 0, 0);
                acc[mt] = a;
            }
            // --- epilogue: dist = ynorm - 2*dot; running argmin (c ascending, strict <) ---
            const int   ccol = wy * 64 + ct * 16;
            const float yn   = Lyn[c0 + ccol + l15];
            const int   cidx = cbase0 + c0 + ccol + l15;
#pragma unroll
            for (int mt = 0; mt < 4; ++mt) {
#pragma unroll
                for (int r = 0; r < 4; ++r) {
                    float s = fmaf(-2.f, acc[mt][r], yn);
                    if (s < minv[mt][r]) { minv[mt][r] = s; mini[mt][r] = cidx; }
                }
            }
        }

        // --- drain: tile tt+1 DMA has been landing under the MFMAs above ---
        asm volatile("s_waitcnt vmcnt(0)" ::: "memory");
        asm volatile("s_waitcnt lgkmcnt(0)" ::: "memory");
        __builtin_amdgcn_s_barrier();
        cur ^= 1;
    }

    // --- cross-lane: reduce over the 16 col-lanes (xor on low 4 lane bits) ---
#pragma unroll
    for (int mt = 0; mt < 4; ++mt) {
#pragma unroll
        for (int r = 0; r < 4; ++r) {
            float v = minv[mt][r];
            int   i = mini[mt][r];
#pragma unroll
            for (int m = 1; m <= 8; m <<= 1) {
                float ov = __shfl_xor(v, m, 64);
                int   oi = __shfl_xor(i, m, 64);
                if (ov < v || (ov == v && oi < i)) { v = ov; i = oi; }
            }
            if (l15 == 0) {
                int qoff = wq * 64 + mt * 16 + lq * 4 + r;   // row within block
                RedV[wy][qoff] = v;
                RedI[wy][qoff] = i;
            }
        }
    }
    __syncthreads();

    // --- combine c-halves, then FENCE-FREE cross-split combine via atomics ---
    if (t < BQ) {
        float v0 = RedV[0][t]; int i0 = RedI[0][t];
        float v1 = RedV[1][t]; int i1 = RedI[1][t];
        if (v1 < v0 || (v1 == v0 && i1 < i0)) { v0 = v1; i0 = i1; }
        atomicMin(&packed[qblk + t], pack_di(v0, i0));   // device-scope, coherent
    }
    // ensure this block's atomicMins are globally performed before the ticket
    asm volatile("s_waitcnt vmcnt(0)" ::: "memory");
    __syncthreads();
    if (t == 0) fin = (atomicAdd(&cnt[bx], 1) == CSPLIT - 1);
    __syncthreads();
    if (fin && t < BQ) {
        // atomic read-back (atomicMin with identity) -> final packed value
        unsigned long long v = atomicMin(&packed[qblk + t], ~0ull);
        out[qblk + t] = (int)(unsigned int)(v & 0xFFFFFFFFu);
    }
}

// ---------------------------------------------------------------------------
extern "C" void kernel_launch(void* const* d_in, const int* in_sizes, int n_in,
                              void* d_out, int out_size, void* d_ws, size_t ws_size,
                              hipStream_t stream) {
    const float* X = (const float*)d_in[0];   // [16384, 64]
    const float* W = (const float*)d_in[1];   // [8192, 64]

    // ws layout: Wh(1MB) | Wl(1MB) | ynorm(32KB) | packed(128KB) | cnt(512B)
    _Float16* Wh    = (_Float16*)d_ws;
    _Float16* Wl    = Wh + (size_t)NTOK * EMB;
    float*    ynorm = (float*)(Wl + (size_t)NTOK * EMB);
    unsigned long long* packed = (unsigned long long*)(ynorm + NTOK);
    int*      cnt   = (int*)(packed + NQ);
    int*      out   = (int*)d_out;

    prep_kernel<<<(NTOK * 8) / TPB, TPB, 0, stream>>>(W, Wh, Wl, ynorm, packed, cnt);
    dim3 grid(NXBLK, CSPLIT);
    vq_mfma_kernel<<<grid, TPB, 0, stream>>>(X, Wh, Wl, ynorm, packed, cnt, out);
}

// Round 12
// 108.228 us; speedup vs baseline: 1.6928x; 1.0469x over previous
//
#include <hip/hip_runtime.h>
#include <math.h>

// Problem: X[16384,64] fp32, W[8192,64] fp32 -> argmin_c ||x-w_c||^2 (int32)
#define EMB     64
#define NTOK    8192
#define NQ      16384
#define TPB     256               // 4 waves: 2 q-halves x 2 c-halves
#define CSPLIT  4
#define CRANGE  (NTOK / CSPLIT)   // 2048 codewords per y-split
#define BQ      128               // query rows per block
#define TILE_C  128               // codewords staged in LDS per iteration
#define NT      (CRANGE / TILE_C) // 16 tiles
#define TCH     (TILE_C * EMB)    // halves per tile buffer (8192 = 16KB)
#define NXBLK   (NQ / BQ)         // 128

typedef _Float16 half8 __attribute__((ext_vector_type(8)));
typedef float    f32x4 __attribute__((ext_vector_type(4)));

// async global->LDS DMA, 16B per lane (dest = wave-uniform base + lane*16)
__device__ __forceinline__ void gl2lds16(const _Float16* g, _Float16* l) {
    __builtin_amdgcn_global_load_lds(
        (const __attribute__((address_space(1))) unsigned int*)g,
        (__attribute__((address_space(3))) unsigned int*)l, 16, 0, 0);
}

// monotone float->uint map: m(a) < m(b) iff a < b (no NaNs here)
__device__ __forceinline__ unsigned long long pack_di(float d, int idx) {
    unsigned int u = __float_as_uint(d);
    unsigned int m = (u & 0x80000000u) ? ~u : (u | 0x80000000u);
    return ((unsigned long long)m << 32) | (unsigned int)idx;
}

// ---------------------------------------------------------------------------
// Prep v3 (verified r11) -- COALESCED. One thread per input 8-float segment
// (65536 threads, 256 blocks): thread reads row c = gtid>>3, seg = gtid&7
// (wave covers contiguous 2KB). Writes Wh/Wl in MFMA-FRAGMENT ORDER
// (bit-identical bytes to the r5-r11-verified layout):
//   chunk u = g*128 + kb*64 + lq*16 + r holds W[g*16+r][kb*32+lq*8..+7].
// ynorm via 3-step shfl_xor tree over the 8 same-row lanes.
// Also inits packed[]/cnt[].
// ---------------------------------------------------------------------------
__global__ void prep_kernel(const float* __restrict__ W,
                            _Float16* __restrict__ Wh, _Float16* __restrict__ Wl,
                            float* __restrict__ ynorm,
                            unsigned long long* __restrict__ packed,
                            int* __restrict__ cnt) {
    const int gtid = blockIdx.x * blockDim.x + threadIdx.x;   // 0..65535
    if (gtid < NQ)    packed[gtid] = ~0ull;
    if (gtid < NXBLK) cnt[gtid] = 0;

    const int c   = gtid >> 3;          // input row (0..8191)
    const int seg = gtid & 7;           // 8-float segment within row
    const float* wp = W + (size_t)c * EMB + seg * 8;
    float4 v0 = *(const float4*)wp;     // coalesced: wave covers 2KB contiguous
    float4 v1 = *(const float4*)(wp + 4);
    float xv[8] = {v0.x, v0.y, v0.z, v0.w, v1.x, v1.y, v1.z, v1.w};
    half8 h, l;
    float s8 = 0.f;
#pragma unroll
    for (int j = 0; j < 8; ++j) {
        _Float16 hh = (_Float16)xv[j];
        h[j] = hh;
        l[j] = (_Float16)(xv[j] - (float)hh);
        s8 = fmaf(xv[j], xv[j], s8);
    }
    const int g = c >> 4, r = c & 15, kb = seg >> 2, lq = seg & 3;
    const size_t u = (size_t)g * 128 + kb * 64 + lq * 16 + r;
    *(half8*)(Wh + u * 8) = h;
    *(half8*)(Wl + u * 8) = l;

    // ynorm: tree-sum the 8 segment partials of row c (lanes 8-aligned)
    s8 += __shfl_xor(s8, 1, 64);
    s8 += __shfl_xor(s8, 2, 64);
    s8 += __shfl_xor(s8, 4, 64);
    if (seg == 0) ynorm[c] = s8;
}

// ---------------------------------------------------------------------------
// Main: r11 structure (best measured, 66.0us) + YN-FOLD: A fragments
// pre-scaled by -2 (exact in fp16: pure exponent shift, incl. the lo
// residual), accumulator initialized with yn (D-layout col = lane&15 ->
// yn uniform across a lane's 4 acc regs). The MFMA chain then yields dist
// DIRECTLY -> epilogue is cmp+select only (kills 64 fmaf/tile/thread).
// Only rounding-association changes (~1e-6 class, same tolerance class
// verified absmax=0 since r5).
// Session ledger (measured -- do not regress):
//  - __launch_bounds__ arg2: 3 -> cap ~170 ok; 2 -> ~128 ok; >=4 -> 64 VGPR
//    = total spill (r2, r9).
//  - coop grid.sync fusion 3x slower (r4); __threadfence finisher +34us (r5).
//  - sync ablation r6/r7/r8 all ~66us; occupancy worse both regimes (r3/r10).
//  - total-vs-main gap ~47us is fixed harness overhead (r11: prep fix
//    moved total only 3us) -- main kernel is the only live target.
// ---------------------------------------------------------------------------
__global__ __launch_bounds__(TPB, 3) void vq_mfma_kernel(
    const float* __restrict__ X,
    const _Float16* __restrict__ Wh, const _Float16* __restrict__ Wl,
    const float* __restrict__ ynorm,
    unsigned long long* __restrict__ packed,
    int* __restrict__ cnt, int* __restrict__ out)
{
    __shared__ __align__(16) _Float16 LdsH0[TCH];
    __shared__ __align__(16) _Float16 LdsH1[TCH];
    __shared__ __align__(16) _Float16 LdsL0[TCH];
    __shared__ __align__(16) _Float16 LdsL1[TCH];
    __shared__ __align__(16) float    Lyn[CRANGE];
    __shared__ float RedV[2][BQ];
    __shared__ int   RedI[2][BQ];
    __shared__ int   fin;

    const int t    = threadIdx.x;
    const int lane = t & 63;
    const int wid  = t >> 6;       // 0..3
    const int wq   = wid & 1;      // q half (0/1)
    const int wy   = wid >> 1;     // c half (0/1)
    const int l15  = lane & 15;
    const int lq   = lane >> 4;    // 0..3

    const int bx     = blockIdx.x;
    const int qblk   = bx * BQ;
    const int qbase  = qblk + wq * 64;
    const int cbase0 = blockIdx.y * CRANGE;

    // --- issue tile-0 DMA first so it overlaps prologue work ---
    {
        const size_t gsbase = (size_t)(cbase0 >> 4) * 1024;   // halves
#pragma unroll
        for (int i = 0; i < 4; ++i) {
            const int jw = i * 256 + wid * 64;                // wave-uniform chunk base
            gl2lds16(Wh + gsbase + (size_t)(jw + lane) * 8, LdsH0 + (size_t)jw * 8);
            gl2lds16(Wl + gsbase + (size_t)(jw + lane) * 8, LdsL0 + (size_t)jw * 8);
        }
    }

    // --- stage the block's full ynorm range once ---
    for (int u = t; u < CRANGE / 4; u += TPB)
        ((float4*)Lyn)[u] = ((const float4*)(ynorm + cbase0))[u];

    // --- A fragments PRE-SCALED by -2 (exact): X rows (qbase + mt*16 + l15),
    //     k = kb*32 + lq*8 + j. Products become -2*x*w; acc init = yn. ---
    half8 ah[4][2], al[4][2];
#pragma unroll
    for (int mt = 0; mt < 4; ++mt) {
#pragma unroll
        for (int kb = 0; kb < 2; ++kb) {
            const float* xp = X + (size_t)(qbase + mt * 16 + l15) * EMB + kb * 32 + lq * 8;
            float4 v0 = *(const float4*)xp;
            float4 v1 = *(const float4*)(xp + 4);
            float xv[8] = {v0.x, v0.y, v0.z, v0.w, v1.x, v1.y, v1.z, v1.w};
            half8 h, l;
#pragma unroll
            for (int j = 0; j < 8; ++j) {
                _Float16 hh = (_Float16)xv[j];               // hi split (unscaled)
                float    rr = xv[j] - (float)hh;             // exact residual
                h[j] = (_Float16)(-2.0f * (float)hh);        // exact x2 scale
                l[j] = (_Float16)(-2.0f * rr);               // exact x2 scale
            }
            ah[mt][kb] = h;
            al[mt][kb] = l;
        }
    }

    float minv[4][4];
    int   mini[4][4];
#pragma unroll
    for (int mt = 0; mt < 4; ++mt)
#pragma unroll
        for (int r = 0; r < 4; ++r) { minv[mt][r] = INFINITY; mini[mt][r] = 0; }

    __syncthreads();   // tile0 DMA + Lyn writes visible

    int cur = 0;
    for (int tt = 0; tt < NT; ++tt) {
        // --- STAGE tile tt+1 into the other buffer (async DMA, in flight under MFMAs) ---
        if (tt + 1 < NT) {
            const size_t gsbase = (size_t)((cbase0 + (tt + 1) * TILE_C) >> 4) * 1024;
            _Float16* dH = (cur ^ 1) ? LdsH1 : LdsH0;
            _Float16* dL = (cur ^ 1) ? LdsL1 : LdsL0;
#pragma unroll
            for (int i = 0; i < 4; ++i) {
                const int jw = i * 256 + wid * 64;
                gl2lds16(Wh + gsbase + (size_t)(jw + lane) * 8, dH + (size_t)jw * 8);
                gl2lds16(Wl + gsbase + (size_t)(jw + lane) * 8, dL + (size_t)jw * 8);
            }
        }

        // --- COMPUTE tile tt from buf cur ---
        const _Float16* LH = cur ? LdsH1 : LdsH0;
        const _Float16* LL = cur ? LdsL1 : LdsL0;
        const int c0 = tt * TILE_C;
#pragma unroll
        for (int ct = 0; ct < 4; ++ct) {
            const int chunk0 = (wy * 4 + ct) * 128 + lane;   // 64 consecutive chunks/wave
            const int ccol   = wy * 64 + ct * 16;
            const float yn   = Lyn[c0 + ccol + l15];         // col depends on l15 only
            const f32x4 yn4  = {yn, yn, yn, yn};             // acc init = yn (D: col=lane&15)
            half8 bh0 = *(const half8*)(LH + (size_t)chunk0 * 8);
            half8 bl0 = *(const half8*)(LL + (size_t)chunk0 * 8);
            half8 bh1 = *(const half8*)(LH + (size_t)(chunk0 + 64) * 8);
            half8 bl1 = *(const half8*)(LL + (size_t)(chunk0 + 64) * 8);
            f32x4 acc[4];
#pragma unroll
            for (int mt = 0; mt < 4; ++mt) {
                // 3-term x (-2) with yn-init: acc ends as dist directly
                f32x4 a = __builtin_amdgcn_mfma_f32_16x16x32_f16(al[mt][0], bh0, yn4, 0, 0, 0);
                a = __builtin_amdgcn_mfma_f32_16x16x32_f16(ah[mt][0], bl0, a, 0, 0, 0);
                a = __builtin_amdgcn_mfma_f32_16x16x32_f16(ah[mt][0], bh0, a, 0, 0, 0);
                a = __builtin_amdgcn_mfma_f32_16x16x32_f16(al[mt][1], bh1, a, 0, 0, 0);
                a = __builtin_amdgcn_mfma_f32_16x16x32_f16(ah[mt][1], bl1, a, 0, 0, 0);
                a = __builtin_amdgcn_mfma_f32_16x16x32_f16(ah[mt][1], bh1, a, 0, 0, 0);
                acc[mt] = a;
            }
            // --- epilogue: acc IS dist; running argmin (c ascending, strict <) ---
            const int cidx = cbase0 + c0 + ccol + l15;
#pragma unroll
            for (int mt = 0; mt < 4; ++mt) {
#pragma unroll
                for (int r = 0; r < 4; ++r) {
                    float s = acc[mt][r];
                    if (s < minv[mt][r]) { minv[mt][r] = s; mini[mt][r] = cidx; }
                }
            }
        }

        // --- drain: tile tt+1 DMA has been landing under the MFMAs above ---
        asm volatile("s_waitcnt vmcnt(0)" ::: "memory");
        asm volatile("s_waitcnt lgkmcnt(0)" ::: "memory");
        __builtin_amdgcn_s_barrier();
        cur ^= 1;
    }

    // --- cross-lane: reduce over the 16 col-lanes (xor on low 4 lane bits) ---
#pragma unroll
    for (int mt = 0; mt < 4; ++mt) {
#pragma unroll
        for (int r = 0; r < 4; ++r) {
            float v = minv[mt][r];
            int   i = mini[mt][r];
#pragma unroll
            for (int m = 1; m <= 8; m <<= 1) {
                float ov = __shfl_xor(v, m, 64);
                int   oi = __shfl_xor(i, m, 64);
                if (ov < v || (ov == v && oi < i)) { v = ov; i = oi; }
            }
            if (l15 == 0) {
                int qoff = wq * 64 + mt * 16 + lq * 4 + r;   // row within block
                RedV[wy][qoff] = v;
                RedI[wy][qoff] = i;
            }
        }
    }
    __syncthreads();

    // --- combine c-halves, then FENCE-FREE cross-split combine via atomics ---
    if (t < BQ) {
        float v0 = RedV[0][t]; int i0 = RedI[0][t];
        float v1 = RedV[1][t]; int i1 = RedI[1][t];
        if (v1 < v0 || (v1 == v0 && i1 < i0)) { v0 = v1; i0 = i1; }
        atomicMin(&packed[qblk + t], pack_di(v0, i0));   // device-scope, coherent
    }
    // ensure this block's atomicMins are globally performed before the ticket
    asm volatile("s_waitcnt vmcnt(0)" ::: "memory");
    __syncthreads();
    if (t == 0) fin = (atomicAdd(&cnt[bx], 1) == CSPLIT - 1);
    __syncthreads();
    if (fin && t < BQ) {
        // atomic read-back (atomicMin with identity) -> final packed value
        unsigned long long v = atomicMin(&packed[qblk + t], ~0ull);
        out[qblk + t] = (int)(unsigned int)(v & 0xFFFFFFFFu);
    }
}

// ---------------------------------------------------------------------------
extern "C" void kernel_launch(void* const* d_in, const int* in_sizes, int n_in,
                              void* d_out, int out_size, void* d_ws, size_t ws_size,
                              hipStream_t stream) {
    const float* X = (const float*)d_in[0];   // [16384, 64]
    const float* W = (const float*)d_in[1];   // [8192, 64]

    // ws layout: Wh(1MB) | Wl(1MB) | ynorm(32KB) | packed(128KB) | cnt(512B)
    _Float16* Wh    = (_Float16*)d_ws;
    _Float16* Wl    = Wh + (size_t)NTOK * EMB;
    float*    ynorm = (float*)(Wl + (size_t)NTOK * EMB);
    unsigned long long* packed = (unsigned long long*)(ynorm + NTOK);
    int*      cnt   = (int*)(packed + NQ);
    int*      out   = (int*)d_out;

    prep_kernel<<<(NTOK * 8) / TPB, TPB, 0, stream>>>(W, Wh, Wl, ynorm, packed, cnt);
    dim3 grid(NXBLK, CSPLIT);
    vq_mfma_kernel<<<grid, TPB, 0, stream>>>(X, Wh, Wl, ynorm, packed, cnt, out);
}